// Round 13
// baseline (53.477 us; speedup 1.0000x reference)
//
#include <hip/hip_runtime.h>
#include <hip/hip_bf16.h>

#define BB 8
#define NN 1024
#define HH 512
#define NEG 0.2f

typedef float f32x4 __attribute__((ext_vector_type(4)));
typedef short bf16x8 __attribute__((ext_vector_type(8)));
typedef unsigned int u32;

__device__ __forceinline__ unsigned short f2bf(float f) {
    union { float f; u32 u; } a; a.f = f;
    u32 u = a.u;
    u += 0x7fffu + ((u >> 16) & 1u);   // round-to-nearest-even
    return (unsigned short)(u >> 16);
}

// Kernel 1: per (batch, 16-row j-tile): s_src/s_dst dots + X^T bf16 [b][h][j]
// 512 thr, grid 512 (2 blocks/CU). Coalesced X reads, 32B contiguous XT writes.
__global__ __launch_bounds__(512) void prep_kernel(
    const float* __restrict__ x, const float* __restrict__ wsrc,
    const float* __restrict__ wdst, float* __restrict__ ssrc,
    float* __restrict__ sdst, unsigned short* __restrict__ xt)
{
    __shared__ __align__(16) unsigned short lt[16][528];

    int bid = blockIdx.x;
    int b = bid & 7;
    int j0 = (bid >> 3) * 16;
    int t = threadIdx.x;
    int r = t >> 5;            // 0..15: row in tile (32 threads per row)
    int l = t & 31;

    const float* xrow = x + ((size_t)(b * NN + j0 + r)) * HH;
    float psrc = 0.f, pdst = 0.f;
    #pragma unroll
    for (int q = 0; q < 4; ++q) {
        int h = q * 128 + l * 4;
        f32x4 v = *(const f32x4*)(xrow + h);
        f32x4 a = *(const f32x4*)(wsrc + h);
        f32x4 d = *(const f32x4*)(wdst + h);
        psrc += v[0]*a[0] + v[1]*a[1] + v[2]*a[2] + v[3]*a[3];
        pdst += v[0]*d[0] + v[1]*d[1] + v[2]*d[2] + v[3]*d[3];
        u32 lo = (u32)f2bf(v[0]) | ((u32)f2bf(v[1]) << 16);
        u32 hi = (u32)f2bf(v[2]) | ((u32)f2bf(v[3]) << 16);
        *(u32*)&lt[r][h + 0] = lo;
        *(u32*)&lt[r][h + 2] = hi;
    }
    #pragma unroll
    for (int k = 1; k < 32; k <<= 1) {
        psrc += __shfl_xor(psrc, k);
        pdst += __shfl_xor(pdst, k);
    }
    if (l == 0) {
        ssrc[b * NN + j0 + r] = psrc;
        sdst[b * NN + j0 + r] = pdst;
    }
    __syncthreads();

    unsigned short v[16];
    #pragma unroll
    for (int rr = 0; rr < 16; ++rr) v[rr] = lt[rr][t];
    unsigned short* dst = xt + ((size_t)(b * HH + t)) * NN + j0;
    #pragma unroll
    for (int q = 0; q < 2; ++q) {
        bf16x8 pk;
        #pragma unroll
        for (int e = 0; e < 8; ++e) pk[e] = (short)v[q*8 + e];
        *(bf16x8*)(dst + q * 8) = pk;
    }
}

// Kernel 2: FUSED softmax + PV, v3 = R9's numerically-verified kernel with
// __launch_bounds__(512, 2). R9 ran at VGPR_Count=56: the compiler's occupancy
// heuristic spilled/serialized a4[16]+sc[64], collapsing the 16-deep adjacency
// MLP to ~2 -> adj read at 823 GB/s = the whole 45us. min-2-waves/EU raises the
// VGPR cap to 256 so the declared ILP actually materializes.
// Block = (b, 32-row i-tile), grid 256, 512 thr.
// Sweep 1: 16 adjacency int4 loads upfront, scores in regs, 16-lane softmax,
//          normalized bf16 P -> 64KB swizzled LDS, ONE barrier.
// Sweep 2: barrier-free K-loop: A register-direct from L2-hot XT[b] (XCD-affine,
//          1MB/L2), B from LDS, 16x16x32 MFMA, full unroll.
__global__ __launch_bounds__(512, 2) void fgat_kernel(
    const float* __restrict__ ssrc, const float* __restrict__ sdst,
    const int* __restrict__ adj, const float* __restrict__ bptr,
    const unsigned short* __restrict__ xt, float* __restrict__ out)
{
    __shared__ __align__(16) float sd[NN];                 // 4KB: sdst[b][:]
    __shared__ float ss[32];
    __shared__ __align__(16) unsigned short Pl[32 * NN];   // 64KB: P, swizzled

    int bid = blockIdx.x;
    int b = bid & 7;               // XCD-affine: XT[b] hot in this XCD's L2
    int i0 = (bid >> 3) * 32;
    int t = threadIdx.x;
    int lane = t & 63;
    int w = t >> 6;                // wave 0..7: h-chunk of 64
    int il = t >> 4;               // 0..31: i-row (16 threads per row)
    int jq = t & 15;               // j-quad group within each 64-j tile

    *(float2*)&sd[t * 2] = *(const float2*)&sdst[b * NN + t * 2];
    if (t < 32) ss[t] = ssrc[b * NN + i0 + t];
    __syncthreads();

    // ---- Sweep 1 ----
    int ig = i0 + il;
    const int* arow = adj + ((size_t)(b * NN + ig)) * NN;

    // ALL adjacency loads upfront: 16 int4 in flight per thread (64 VGPR)
    int4 a4[16];
    #pragma unroll
    for (int T = 0; T < 16; ++T) a4[T] = *(const int4*)(arow + T * 64 + jq * 4);

    float si = ss[il] + bptr[0];
    float sc[64];
    float m = -1e30f;
    #pragma unroll
    for (int T = 0; T < 16; ++T) {
        int j = T * 64 + jq * 4;
        f32x4 sv = *(const f32x4*)&sd[j];
        float s0 = si + sv[0]; s0 = s0 > 0.f ? s0 : NEG * s0;
        float s1 = si + sv[1]; s1 = s1 > 0.f ? s1 : NEG * s1;
        float s2 = si + sv[2]; s2 = s2 > 0.f ? s2 : NEG * s2;
        float s3 = si + sv[3]; s3 = s3 > 0.f ? s3 : NEG * s3;
        sc[T*4+0] = (a4[T].x != 0 || (j + 0) == ig) ? s0 : -1e30f;
        sc[T*4+1] = (a4[T].y != 0 || (j + 1) == ig) ? s1 : -1e30f;
        sc[T*4+2] = (a4[T].z != 0 || (j + 2) == ig) ? s2 : -1e30f;
        sc[T*4+3] = (a4[T].w != 0 || (j + 3) == ig) ? s3 : -1e30f;
        m = fmaxf(m, fmaxf(fmaxf(sc[T*4+0], sc[T*4+1]), fmaxf(sc[T*4+2], sc[T*4+3])));
    }
    #pragma unroll
    for (int k = 1; k < 16; k <<= 1) m = fmaxf(m, __shfl_xor(m, k));
    float sum = 0.f;
    #pragma unroll
    for (int k = 0; k < 64; ++k) { float e = __expf(sc[k] - m); sc[k] = e; sum += e; }
    #pragma unroll
    for (int k = 1; k < 16; k <<= 1) sum += __shfl_xor(sum, k);
    float inv = 1.f / sum;

    // write normalized P (bf16) into swizzled LDS: elem (row,j) at byte
    // (row*2048 + j*2) ^ ((row&7)<<4)
    #pragma unroll
    for (int T = 0; T < 16; ++T) {
        int j = T * 64 + jq * 4;
        u32 lo = (u32)f2bf(sc[T*4+0] * inv) | ((u32)f2bf(sc[T*4+1] * inv) << 16);
        u32 hi = (u32)f2bf(sc[T*4+2] * inv) | ((u32)f2bf(sc[T*4+3] * inv) << 16);
        int byte = ((il * NN + j) * 2) ^ ((il & 7) << 4);
        *(uint2*)((char*)Pl + byte) = make_uint2(lo, hi);
    }
    __syncthreads();   // the ONLY barrier: P fully resident

    // ---- Sweep 2: barrier-free GEMM. out^T: M=h (A=XT), N=i (B=P-LDS), K=j ----
    int g = lane >> 4;
    int ln = lane & 15;
    const unsigned short* abase = xt + ((size_t)(b * HH + w * 64 + ln)) * NN + g * 8;

    // B read bases: XOR spans bits 4-6, so kk*64 and g*16 are INSIDE the XOR'd
    // expression; only js*128 (bits 7-10, carry-free) is added at use (R8 lesson).
    const char* pb[2][2];
    #pragma unroll
    for (int nb = 0; nb < 2; ++nb) {
        int row = nb * 16 + ln;
        #pragma unroll
        for (int kk = 0; kk < 2; ++kk)
            pb[nb][kk] = (const char*)Pl + ((row * 2048 + kk * 64 + g * 16) ^ ((row & 7) << 4));
    }

    f32x4 acc[4][2];
    #pragma unroll
    for (int ma = 0; ma < 4; ++ma)
        #pragma unroll
        for (int nb = 0; nb < 2; ++nb)
            acc[ma][nb] = (f32x4){0.f, 0.f, 0.f, 0.f};

    #pragma unroll
    for (int js = 0; js < 16; ++js) {
        bf16x8 af[4][2], bfr[2][2];
        #pragma unroll
        for (int ma = 0; ma < 4; ++ma)
            #pragma unroll
            for (int kk = 0; kk < 2; ++kk)
                af[ma][kk] = *(const bf16x8*)(abase + (size_t)(ma * 16) * NN + js * 64 + kk * 32);
        #pragma unroll
        for (int nb = 0; nb < 2; ++nb)
            #pragma unroll
            for (int kk = 0; kk < 2; ++kk)
                bfr[nb][kk] = *(const bf16x8*)(pb[nb][kk] + js * 128);
        #pragma unroll
        for (int kk = 0; kk < 2; ++kk)
            #pragma unroll
            for (int ma = 0; ma < 4; ++ma)
                #pragma unroll
                for (int nb = 0; nb < 2; ++nb)
                    acc[ma][nb] = __builtin_amdgcn_mfma_f32_16x16x32_bf16(af[ma][kk], bfr[nb][kk], acc[ma][nb], 0, 0, 0);
    }

    // D: h = w*64 + ma*16 + g*4 + r, i = i0 + nb*16 + ln  (P pre-normalized)
    #pragma unroll
    for (int nb = 0; nb < 2; ++nb) {
        int i = i0 + nb * 16 + ln;
        #pragma unroll
        for (int ma = 0; ma < 4; ++ma) {
            float* dst = out + ((size_t)(b * NN + i)) * HH + w * 64 + ma * 16 + g * 4;
            *(f32x4*)dst = acc[ma][nb];
        }
    }
}

extern "C" void kernel_launch(void* const* d_in, const int* in_sizes, int n_in,
                              void* d_out, int out_size, void* d_ws, size_t ws_size,
                              hipStream_t stream) {
    const float* x    = (const float*)d_in[0];
    const int*   adj  = (const int*)d_in[1];
    const float* wsrc = (const float*)d_in[2];
    const float* wdst = (const float*)d_in[3];
    const float* bias = (const float*)d_in[4];
    float* out = (float*)d_out;

    // ws layout: ssrc(32KB) | sdst(32KB) | XT bf16 (8MB)
    float* ssrc = (float*)d_ws;
    float* sdst = ssrc + BB * NN;
    unsigned short* xt = (unsigned short*)(sdst + BB * NN);

    prep_kernel<<<dim3(BB * (NN / 16)), dim3(512), 0, stream>>>(x, wsrc, wdst, ssrc, sdst, xt);
    fgat_kernel<<<dim3(BB * (NN / 32)), dim3(512), 0, stream>>>(ssrc, sdst, adj, bias, xt, out);
}

// Round 14
// 53.432 us; speedup vs baseline: 1.0008x; 1.0008x over previous
//
#include <hip/hip_runtime.h>
#include <hip/hip_bf16.h>

#define BB 8
#define NN 1024
#define HH 512
#define NEG 0.2f

typedef float f32x4 __attribute__((ext_vector_type(4)));
typedef float f32x16 __attribute__((ext_vector_type(16)));
typedef short bf16x8 __attribute__((ext_vector_type(8)));
typedef unsigned int u32;

__device__ __forceinline__ unsigned short f2bf(float f) {
    union { float f; u32 u; } a; a.f = f;
    u32 u = a.u;
    u += 0x7fffu + ((u >> 16) & 1u);   // round-to-nearest-even
    return (unsigned short)(u >> 16);
}

__device__ __forceinline__ void gload16(const void* g, void* l) {
    __builtin_amdgcn_global_load_lds(
        (const __attribute__((address_space(1))) unsigned int*)g,
        (__attribute__((address_space(3))) unsigned int*)l, 16, 0, 0);
}

// Kernel 1: per (batch, 16-row j-tile): s_src/s_dst dots + X^T bf16 [b][h][j]
__global__ __launch_bounds__(512) void prep_kernel(
    const float* __restrict__ x, const float* __restrict__ wsrc,
    const float* __restrict__ wdst, float* __restrict__ ssrc,
    float* __restrict__ sdst, unsigned short* __restrict__ xt)
{
    __shared__ __align__(16) unsigned short lt[16][528];

    int bid = blockIdx.x;
    int b = bid & 7;
    int j0 = (bid >> 3) * 16;
    int t = threadIdx.x;
    int r = t >> 5;            // 0..15: row in tile (32 threads per row)
    int l = t & 31;

    const float* xrow = x + ((size_t)(b * NN + j0 + r)) * HH;
    float psrc = 0.f, pdst = 0.f;
    #pragma unroll
    for (int q = 0; q < 4; ++q) {
        int h = q * 128 + l * 4;
        f32x4 v = *(const f32x4*)(xrow + h);
        f32x4 a = *(const f32x4*)(wsrc + h);
        f32x4 d = *(const f32x4*)(wdst + h);
        psrc += v[0]*a[0] + v[1]*a[1] + v[2]*a[2] + v[3]*a[3];
        pdst += v[0]*d[0] + v[1]*d[1] + v[2]*d[2] + v[3]*d[3];
        u32 lo = (u32)f2bf(v[0]) | ((u32)f2bf(v[1]) << 16);
        u32 hi = (u32)f2bf(v[2]) | ((u32)f2bf(v[3]) << 16);
        *(u32*)&lt[r][h + 0] = lo;
        *(u32*)&lt[r][h + 2] = hi;
    }
    #pragma unroll
    for (int k = 1; k < 32; k <<= 1) {
        psrc += __shfl_xor(psrc, k);
        pdst += __shfl_xor(pdst, k);
    }
    if (l == 0) {
        ssrc[b * NN + j0 + r] = psrc;
        sdst[b * NN + j0 + r] = pdst;
    }
    __syncthreads();

    unsigned short v[16];
    #pragma unroll
    for (int rr = 0; rr < 16; ++rr) v[rr] = lt[rr][t];
    unsigned short* dst = xt + ((size_t)(b * HH + t)) * NN + j0;
    #pragma unroll
    for (int q = 0; q < 2; ++q) {
        bf16x8 pk;
        #pragma unroll
        for (int e = 0; e < 8; ++e) pk[e] = (short)v[q*8 + e];
        *(bf16x8*)(dst + q * 8) = pk;
    }
}

// Kernel 2: softmax rows. 1 wave = 1 adjacency row. Writes NORMALIZED P (bf16).
__global__ __launch_bounds__(256) void softmax_kernel(
    const float* __restrict__ ssrc, const float* __restrict__ sdst,
    const int* __restrict__ adj, const float* __restrict__ bptr,
    unsigned short* __restrict__ P)
{
    __shared__ __align__(16) float sd[NN];

    int bid = blockIdx.x;
    int b = bid & 7;
    int r0 = (bid >> 3) * 4;
    int t = threadIdx.x;
    int lane = t & 63;
    int w = t >> 6;

    *(f32x4*)&sd[t * 4] = *(const f32x4*)&sdst[b * NN + t * 4];
    __syncthreads();

    int ig = r0 + w;
    float si = ssrc[b * NN + ig] + bptr[0];
    const int* arow = adj + ((size_t)b * NN + ig) * NN;

    float sc[16];
    float m = -1e30f;
    #pragma unroll
    for (int it = 0; it < 4; ++it) {
        int j = it * 256 + lane * 4;
        int4 a4 = *(const int4*)(arow + j);
        f32x4 sv = *(const f32x4*)&sd[j];
        float s0 = si + sv[0]; s0 = s0 > 0.f ? s0 : NEG * s0;
        float s1 = si + sv[1]; s1 = s1 > 0.f ? s1 : NEG * s1;
        float s2 = si + sv[2]; s2 = s2 > 0.f ? s2 : NEG * s2;
        float s3 = si + sv[3]; s3 = s3 > 0.f ? s3 : NEG * s3;
        sc[it*4+0] = (a4.x != 0 || (j + 0) == ig) ? s0 : -1e30f;
        sc[it*4+1] = (a4.y != 0 || (j + 1) == ig) ? s1 : -1e30f;
        sc[it*4+2] = (a4.z != 0 || (j + 2) == ig) ? s2 : -1e30f;
        sc[it*4+3] = (a4.w != 0 || (j + 3) == ig) ? s3 : -1e30f;
        m = fmaxf(m, fmaxf(fmaxf(sc[it*4+0], sc[it*4+1]), fmaxf(sc[it*4+2], sc[it*4+3])));
    }
    #pragma unroll
    for (int k = 1; k < 64; k <<= 1) m = fmaxf(m, __shfl_xor(m, k));
    float sum = 0.f;
    #pragma unroll
    for (int k = 0; k < 16; ++k) { float e = __expf(sc[k] - m); sc[k] = e; sum += e; }
    #pragma unroll
    for (int k = 1; k < 64; k <<= 1) sum += __shfl_xor(sum, k);
    float inv = 1.f / sum;

    unsigned short* prow = P + ((size_t)b * NN + ig) * NN;
    #pragma unroll
    for (int it = 0; it < 4; ++it) {
        int j = it * 256 + lane * 4;
        u32 lo = (u32)f2bf(sc[it*4+0] * inv) | ((u32)f2bf(sc[it*4+1] * inv) << 16);
        u32 hi = (u32)f2bf(sc[it*4+2] * inv) | ((u32)f2bf(sc[it*4+3] * inv) << 16);
        *(uint2*)(prow + j) = make_uint2(lo, hi);
    }
}

// Kernel 3 v5.2 (unchanged from R12, known-correct). Launched TWICE this round
// (idempotent) to measure pv's duration exactly: pv = Δtotal − ~0.75us gap.
__global__ __launch_bounds__(512) void pv_kernel(
    const unsigned short* __restrict__ P, const unsigned short* __restrict__ xt,
    float* __restrict__ out)
{
    __shared__ __align__(16) unsigned short LDSq[3 * 8192 * 2]; // 96KB
    unsigned short* As = LDSq;               // 3 bufs x 16KB  [128h][64k] swizzled
    unsigned short* Bs = LDSq + 3 * 8192;    // 3 bufs x 16KB  [128i][64k] swizzled

    int bid = blockIdx.x;
    int b = bid & 7;              // XCD-affine
    int tt = bid >> 3;            // 0..31
    int h0 = (tt & 3) * 128;
    int i0 = (tt >> 2) * 128;
    int t = threadIdx.x;
    int lane = t & 63;
    int w = t >> 6;
    int ks = w >> 2;              // parity group: 0 = even K-steps, 1 = odd
    int wsub = w & 3;
    int wm = wsub & 1;            // h-half (64)
    int wn = wsub >> 1;           // i-half (64)
    int r32 = lane & 31;
    int hi = lane >> 5;

    int row0 = t >> 3;
    int c = t & 7;
    int sj = (c ^ (row0 & 7)) * 8;
    const unsigned short* gA0 = xt + ((size_t)(b * HH + h0 + row0)) * NN + sj;
    const unsigned short* gA1 = gA0 + (size_t)64 * NN;
    const unsigned short* gB0 = P + ((size_t)(b * NN + i0 + row0)) * NN + sj;
    const unsigned short* gB1 = gB0 + (size_t)64 * NN;
    unsigned short* lA0 = As + t * 8;          // rows 0..63
    unsigned short* lA1 = As + 4096 + t * 8;   // rows 64..127
    unsigned short* lB0 = Bs + t * 8;
    unsigned short* lB1 = Bs + 4096 + t * 8;

    const char* Ab[2]; int aswz[2];
    #pragma unroll
    for (int ma = 0; ma < 2; ++ma) {
        int row = wm * 64 + ma * 32 + r32;
        Ab[ma] = (const char*)As + row * 128;
        aswz[ma] = (row & 7) << 4;
    }
    const char* Bb[2]; int bswz[2];
    #pragma unroll
    for (int nb = 0; nb < 2; ++nb) {
        int row = wn * 64 + nb * 32 + r32;
        Bb[nb] = (const char*)Bs + row * 128;
        bswz[nb] = (row & 7) << 4;
    }

    f32x16 acc00 = {}, acc01 = {}, acc10 = {}, acc11 = {};

    auto stage = [&](int p, int js) {
        int joff = js * 64;
        gload16(gA0 + joff, lA0 + p * 8192);
        gload16(gA1 + joff, lA1 + p * 8192);
        gload16(gB0 + joff, lB0 + p * 8192);
        gload16(gB1 + joff, lB1 + p * 8192);
    };
    auto compute = [&](int p) {
        int ofs = p * 16384;
        #pragma unroll
        for (int cc = 0; cc < 4; ++cc) {
            int koff = cc * 32 + hi * 16;
            bf16x8 af0 = *(const bf16x8*)(Ab[0] + (koff ^ aswz[0]) + ofs);
            bf16x8 af1 = *(const bf16x8*)(Ab[1] + (koff ^ aswz[1]) + ofs);
            bf16x8 bf0 = *(const bf16x8*)(Bb[0] + (koff ^ bswz[0]) + ofs);
            bf16x8 bf1 = *(const bf16x8*)(Bb[1] + (koff ^ bswz[1]) + ofs);
            acc00 = __builtin_amdgcn_mfma_f32_32x32x16_bf16(af0, bf0, acc00, 0, 0, 0);
            acc01 = __builtin_amdgcn_mfma_f32_32x32x16_bf16(af0, bf1, acc01, 0, 0, 0);
            acc10 = __builtin_amdgcn_mfma_f32_32x32x16_bf16(af1, bf0, acc10, 0, 0, 0);
            acc11 = __builtin_amdgcn_mfma_f32_32x32x16_bf16(af1, bf1, acc11, 0, 0, 0);
        }
    };

    stage(0, 0);
    stage(1, 1);
    #pragma unroll
    for (int js = 0; js < 16; ++js) {
        if (js < 15) asm volatile("s_waitcnt vmcnt(4)" ::: "memory");
        else         asm volatile("s_waitcnt vmcnt(0)" ::: "memory");
        __builtin_amdgcn_sched_barrier(0);
        __builtin_amdgcn_s_barrier();
        __builtin_amdgcn_sched_barrier(0);
        if (js + 2 < 16) stage((js + 2) % 3, js + 2);
        if ((js & 1) == ks) compute(js % 3);
    }

    __syncthreads();

    float* red = (float*)LDSq;
    int ridx = (wsub * 64 + lane) * 68;
    if (ks == 1) {
        #pragma unroll
        for (int fq = 0; fq < 4; ++fq) {
            const f32x16* a = fq == 0 ? &acc00 : fq == 1 ? &acc01 : fq == 2 ? &acc10 : &acc11;
            #pragma unroll
            for (int q = 0; q < 4; ++q)
                *(f32x4*)(red + ridx + fq * 16 + q * 4) =
                    (f32x4){(*a)[q*4+0], (*a)[q*4+1], (*a)[q*4+2], (*a)[q*4+3]};
        }
    }
    __syncthreads();
    if (ks == 0) {
        #pragma unroll
        for (int fq = 0; fq < 4; ++fq) {
            f32x16* a = fq == 0 ? &acc00 : fq == 1 ? &acc01 : fq == 2 ? &acc10 : &acc11;
            #pragma unroll
            for (int q = 0; q < 4; ++q) {
                f32x4 v = *(const f32x4*)(red + ridx + fq * 16 + q * 4);
                (*a)[q*4+0] += v[0]; (*a)[q*4+1] += v[1];
                (*a)[q*4+2] += v[2]; (*a)[q*4+3] += v[3];
            }
        }
        #pragma unroll
        for (int ma = 0; ma < 2; ++ma) {
            #pragma unroll
            for (int nb = 0; nb < 2; ++nb) {
                const f32x16* a = ma == 0 ? (nb == 0 ? &acc00 : &acc01)
                                          : (nb == 0 ? &acc10 : &acc11);
                int i = i0 + wn * 64 + nb * 32 + r32;
                float* drow = out + ((size_t)(b * NN + i)) * HH + h0 + wm * 64 + ma * 32;
                #pragma unroll
                for (int q = 0; q < 4; ++q) {
                    f32x4 v = {(*a)[q*4+0], (*a)[q*4+1], (*a)[q*4+2], (*a)[q*4+3]};
                    *(f32x4*)(drow + q * 8 + hi * 4) = v;
                }
            }
        }
    }
}

extern "C" void kernel_launch(void* const* d_in, const int* in_sizes, int n_in,
                              void* d_out, int out_size, void* d_ws, size_t ws_size,
                              hipStream_t stream) {
    const float* x    = (const float*)d_in[0];
    const int*   adj  = (const int*)d_in[1];
    const float* wsrc = (const float*)d_in[2];
    const float* wdst = (const float*)d_in[3];
    const float* bias = (const float*)d_in[4];
    float* out = (float*)d_out;

    // ws layout: ssrc(32KB) | sdst(32KB) | XT bf16 (8MB) | P bf16 (16MB)
    float* ssrc = (float*)d_ws;
    float* sdst = ssrc + BB * NN;
    unsigned short* xt = (unsigned short*)(sdst + BB * NN);
    unsigned short* P  = xt + (size_t)BB * HH * NN;

    prep_kernel<<<dim3(BB * (NN / 16)), dim3(512), 0, stream>>>(x, wsrc, wdst, ssrc, sdst, xt);
    softmax_kernel<<<dim3(BB * NN / 4), dim3(256), 0, stream>>>(ssrc, sdst, adj, bias, P);
    pv_kernel<<<dim3(BB * 4 * 8), dim3(512), 0, stream>>>(P, xt, out);
    // MEASUREMENT: second identical pv launch (idempotent). pv_time = Δtotal − gap.
    pv_kernel<<<dim3(BB * 4 * 8), dim3(512), 0, stream>>>(P, xt, out);
}

// Round 16
// 37.421 us; speedup vs baseline: 1.4291x; 1.4279x over previous
//
#include <hip/hip_runtime.h>
#include <hip/hip_bf16.h>

#define BB 8
#define NN 1024
#define HH 512
#define NEG 0.2f

typedef float f32x4 __attribute__((ext_vector_type(4)));
typedef float f32x16 __attribute__((ext_vector_type(16)));
typedef short bf16x8 __attribute__((ext_vector_type(8)));
typedef int i32x4 __attribute__((ext_vector_type(4)));
typedef unsigned int u32;

__device__ __forceinline__ unsigned short f2bf(float f) {
    union { float f; u32 u; } a; a.f = f;
    u32 u = a.u;
    u += 0x7fffu + ((u >> 16) & 1u);   // round-to-nearest-even
    return (unsigned short)(u >> 16);
}

__device__ __forceinline__ void gload16(const void* g, void* l) {
    __builtin_amdgcn_global_load_lds(
        (const __attribute__((address_space(1))) unsigned int*)g,
        (__attribute__((address_space(3))) unsigned int*)l, 16, 0, 0);
}

// Kernel 1: per (batch, 16-row j-tile): s_src/s_dst dots + X^T bf16 [b][h][j]
// NT loads for x (streamed once) to avoid L2 pollution.
__global__ __launch_bounds__(512) void prep_kernel(
    const float* __restrict__ x, const float* __restrict__ wsrc,
    const float* __restrict__ wdst, float* __restrict__ ssrc,
    float* __restrict__ sdst, unsigned short* __restrict__ xt)
{
    __shared__ __align__(16) unsigned short lt[16][528];

    int bid = blockIdx.x;
    int b = bid & 7;
    int j0 = (bid >> 3) * 16;
    int t = threadIdx.x;
    int r = t >> 5;            // 0..15: row in tile (32 threads per row)
    int l = t & 31;

    const float* xrow = x + ((size_t)(b * NN + j0 + r)) * HH;
    float psrc = 0.f, pdst = 0.f;
    #pragma unroll
    for (int q = 0; q < 4; ++q) {
        int h = q * 128 + l * 4;
        f32x4 v = __builtin_nontemporal_load((const f32x4*)(xrow + h));
        f32x4 a = *(const f32x4*)(wsrc + h);
        f32x4 d = *(const f32x4*)(wdst + h);
        psrc += v[0]*a[0] + v[1]*a[1] + v[2]*a[2] + v[3]*a[3];
        pdst += v[0]*d[0] + v[1]*d[1] + v[2]*d[2] + v[3]*d[3];
        u32 lo = (u32)f2bf(v[0]) | ((u32)f2bf(v[1]) << 16);
        u32 hi = (u32)f2bf(v[2]) | ((u32)f2bf(v[3]) << 16);
        *(u32*)&lt[r][h + 0] = lo;
        *(u32*)&lt[r][h + 2] = hi;
    }
    #pragma unroll
    for (int k = 1; k < 32; k <<= 1) {
        psrc += __shfl_xor(psrc, k);
        pdst += __shfl_xor(pdst, k);
    }
    if (l == 0) {
        ssrc[b * NN + j0 + r] = psrc;
        sdst[b * NN + j0 + r] = pdst;
    }
    __syncthreads();

    unsigned short v[16];
    #pragma unroll
    for (int rr = 0; rr < 16; ++rr) v[rr] = lt[rr][t];
    unsigned short* dst = xt + ((size_t)(b * HH + t)) * NN + j0;
    #pragma unroll
    for (int q = 0; q < 2; ++q) {
        bf16x8 pk;
        #pragma unroll
        for (int e = 0; e < 8; ++e) pk[e] = (short)v[q*8 + e];
        *(bf16x8*)(dst + q * 8) = pk;
    }
}

// Kernel 2: softmax rows. NT loads for adj (streamed once, 32MB) so the
// streaming read + P writes don't thrash each other in L2.
__global__ __launch_bounds__(256) void softmax_kernel(
    const float* __restrict__ ssrc, const float* __restrict__ sdst,
    const int* __restrict__ adj, const float* __restrict__ bptr,
    unsigned short* __restrict__ P)
{
    __shared__ __align__(16) float sd[NN];

    int bid = blockIdx.x;
    int b = bid & 7;
    int r0 = (bid >> 3) * 4;
    int t = threadIdx.x;
    int lane = t & 63;
    int w = t >> 6;

    *(f32x4*)&sd[t * 4] = *(const f32x4*)&sdst[b * NN + t * 4];
    __syncthreads();

    int ig = r0 + w;
    float si = ssrc[b * NN + ig] + bptr[0];
    const int* arow = adj + ((size_t)b * NN + ig) * NN;

    float sc[16];
    float m = -1e30f;
    #pragma unroll
    for (int it = 0; it < 4; ++it) {
        int j = it * 256 + lane * 4;
        i32x4 a4 = __builtin_nontemporal_load((const i32x4*)(arow + j));
        f32x4 sv = *(const f32x4*)&sd[j];
        float s0 = si + sv[0]; s0 = s0 > 0.f ? s0 : NEG * s0;
        float s1 = si + sv[1]; s1 = s1 > 0.f ? s1 : NEG * s1;
        float s2 = si + sv[2]; s2 = s2 > 0.f ? s2 : NEG * s2;
        float s3 = si + sv[3]; s3 = s3 > 0.f ? s3 : NEG * s3;
        sc[it*4+0] = (a4[0] != 0 || (j + 0) == ig) ? s0 : -1e30f;
        sc[it*4+1] = (a4[1] != 0 || (j + 1) == ig) ? s1 : -1e30f;
        sc[it*4+2] = (a4[2] != 0 || (j + 2) == ig) ? s2 : -1e30f;
        sc[it*4+3] = (a4[3] != 0 || (j + 3) == ig) ? s3 : -1e30f;
        m = fmaxf(m, fmaxf(fmaxf(sc[it*4+0], sc[it*4+1]), fmaxf(sc[it*4+2], sc[it*4+3])));
    }
    #pragma unroll
    for (int k = 1; k < 64; k <<= 1) m = fmaxf(m, __shfl_xor(m, k));
    float sum = 0.f;
    #pragma unroll
    for (int k = 0; k < 16; ++k) { float e = __expf(sc[k] - m); sc[k] = e; sum += e; }
    #pragma unroll
    for (int k = 1; k < 64; k <<= 1) sum += __shfl_xor(sum, k);
    float inv = 1.f / sum;

    unsigned short* prow = P + ((size_t)b * NN + ig) * NN;
    #pragma unroll
    for (int it = 0; it < 4; ++it) {
        int j = it * 256 + lane * 4;
        u32 lo = (u32)f2bf(sc[it*4+0] * inv) | ((u32)f2bf(sc[it*4+1] * inv) << 16);
        u32 hi = (u32)f2bf(sc[it*4+2] * inv) | ((u32)f2bf(sc[it*4+3] * inv) << 16);
        *(uint2*)(prow + j) = make_uint2(lo, hi);
    }
}

// Kernel 3 v5.3 = R12's v5.2 + (a) NT stores for out (never re-read: stop
// evicting P/XT panels from the XCD L2) + (b) T5 s_setprio around the MFMA
// cluster (this kernel HAS wave role-split: even/odd compute groups).
__global__ __launch_bounds__(512) void pv_kernel(
    const unsigned short* __restrict__ P, const unsigned short* __restrict__ xt,
    float* __restrict__ out)
{
    __shared__ __align__(16) unsigned short LDSq[3 * 8192 * 2]; // 96KB
    unsigned short* As = LDSq;               // 3 bufs x 16KB  [128h][64k] swizzled
    unsigned short* Bs = LDSq + 3 * 8192;    // 3 bufs x 16KB  [128i][64k] swizzled

    int bid = blockIdx.x;
    int b = bid & 7;              // XCD-affine
    int tt = bid >> 3;            // 0..31
    int h0 = (tt & 3) * 128;
    int i0 = (tt >> 2) * 128;
    int t = threadIdx.x;
    int lane = t & 63;
    int w = t >> 6;
    int ks = w >> 2;              // parity group: 0 = even K-steps, 1 = odd
    int wsub = w & 3;
    int wm = wsub & 1;            // h-half (64)
    int wn = wsub >> 1;           // i-half (64)
    int r32 = lane & 31;
    int hi = lane >> 5;

    int row0 = t >> 3;
    int c = t & 7;
    int sj = (c ^ (row0 & 7)) * 8;
    const unsigned short* gA0 = xt + ((size_t)(b * HH + h0 + row0)) * NN + sj;
    const unsigned short* gA1 = gA0 + (size_t)64 * NN;
    const unsigned short* gB0 = P + ((size_t)(b * NN + i0 + row0)) * NN + sj;
    const unsigned short* gB1 = gB0 + (size_t)64 * NN;
    unsigned short* lA0 = As + t * 8;          // rows 0..63
    unsigned short* lA1 = As + 4096 + t * 8;   // rows 64..127
    unsigned short* lB0 = Bs + t * 8;
    unsigned short* lB1 = Bs + 4096 + t * 8;

    const char* Ab[2]; int aswz[2];
    #pragma unroll
    for (int ma = 0; ma < 2; ++ma) {
        int row = wm * 64 + ma * 32 + r32;
        Ab[ma] = (const char*)As + row * 128;
        aswz[ma] = (row & 7) << 4;
    }
    const char* Bb[2]; int bswz[2];
    #pragma unroll
    for (int nb = 0; nb < 2; ++nb) {
        int row = wn * 64 + nb * 32 + r32;
        Bb[nb] = (const char*)Bs + row * 128;
        bswz[nb] = (row & 7) << 4;
    }

    f32x16 acc00 = {}, acc01 = {}, acc10 = {}, acc11 = {};

    auto stage = [&](int p, int js) {
        int joff = js * 64;
        gload16(gA0 + joff, lA0 + p * 8192);
        gload16(gA1 + joff, lA1 + p * 8192);
        gload16(gB0 + joff, lB0 + p * 8192);
        gload16(gB1 + joff, lB1 + p * 8192);
    };
    auto compute = [&](int p) {
        int ofs = p * 16384;
        __builtin_amdgcn_s_setprio(1);        // T5: favor the MFMA-issuing waves
        #pragma unroll
        for (int cc = 0; cc < 4; ++cc) {
            int koff = cc * 32 + hi * 16;
            bf16x8 af0 = *(const bf16x8*)(Ab[0] + (koff ^ aswz[0]) + ofs);
            bf16x8 af1 = *(const bf16x8*)(Ab[1] + (koff ^ aswz[1]) + ofs);
            bf16x8 bf0 = *(const bf16x8*)(Bb[0] + (koff ^ bswz[0]) + ofs);
            bf16x8 bf1 = *(const bf16x8*)(Bb[1] + (koff ^ bswz[1]) + ofs);
            acc00 = __builtin_amdgcn_mfma_f32_32x32x16_bf16(af0, bf0, acc00, 0, 0, 0);
            acc01 = __builtin_amdgcn_mfma_f32_32x32x16_bf16(af0, bf1, acc01, 0, 0, 0);
            acc10 = __builtin_amdgcn_mfma_f32_32x32x16_bf16(af1, bf0, acc10, 0, 0, 0);
            acc11 = __builtin_amdgcn_mfma_f32_32x32x16_bf16(af1, bf1, acc11, 0, 0, 0);
        }
        __builtin_amdgcn_s_setprio(0);
    };

    stage(0, 0);
    stage(1, 1);
    #pragma unroll
    for (int js = 0; js < 16; ++js) {
        if (js < 15) asm volatile("s_waitcnt vmcnt(4)" ::: "memory");
        else         asm volatile("s_waitcnt vmcnt(0)" ::: "memory");
        __builtin_amdgcn_sched_barrier(0);
        __builtin_amdgcn_s_barrier();
        __builtin_amdgcn_sched_barrier(0);
        if (js + 2 < 16) stage((js + 2) % 3, js + 2);
        if ((js & 1) == ks) compute(js % 3);
    }

    __syncthreads();

    float* red = (float*)LDSq;
    int ridx = (wsub * 64 + lane) * 68;
    if (ks == 1) {
        #pragma unroll
        for (int fq = 0; fq < 4; ++fq) {
            const f32x16* a = fq == 0 ? &acc00 : fq == 1 ? &acc01 : fq == 2 ? &acc10 : &acc11;
            #pragma unroll
            for (int q = 0; q < 4; ++q)
                *(f32x4*)(red + ridx + fq * 16 + q * 4) =
                    (f32x4){(*a)[q*4+0], (*a)[q*4+1], (*a)[q*4+2], (*a)[q*4+3]};
        }
    }
    __syncthreads();
    if (ks == 0) {
        #pragma unroll
        for (int fq = 0; fq < 4; ++fq) {
            f32x16* a = fq == 0 ? &acc00 : fq == 1 ? &acc01 : fq == 2 ? &acc10 : &acc11;
            #pragma unroll
            for (int q = 0; q < 4; ++q) {
                f32x4 v = *(const f32x4*)(red + ridx + fq * 16 + q * 4);
                (*a)[q*4+0] += v[0]; (*a)[q*4+1] += v[1];
                (*a)[q*4+2] += v[2]; (*a)[q*4+3] += v[3];
            }
        }
        // D layout (32x32): col(i) = lane&31, row(h) = (reg&3) + 8*(reg>>2) + 4*hi
        #pragma unroll
        for (int ma = 0; ma < 2; ++ma) {
            #pragma unroll
            for (int nb = 0; nb < 2; ++nb) {
                const f32x16* a = ma == 0 ? (nb == 0 ? &acc00 : &acc01)
                                          : (nb == 0 ? &acc10 : &acc11);
                int i = i0 + wn * 64 + nb * 32 + r32;
                float* drow = out + ((size_t)(b * NN + i)) * HH + h0 + wm * 64 + ma * 32;
                #pragma unroll
                for (int q = 0; q < 4; ++q) {
                    f32x4 v = {(*a)[q*4+0], (*a)[q*4+1], (*a)[q*4+2], (*a)[q*4+3]};
                    __builtin_nontemporal_store(v, (f32x4*)(drow + q * 8 + hi * 4));
                }
            }
        }
    }
}

extern "C" void kernel_launch(void* const* d_in, const int* in_sizes, int n_in,
                              void* d_out, int out_size, void* d_ws, size_t ws_size,
                              hipStream_t stream) {
    const float* x    = (const float*)d_in[0];
    const int*   adj  = (const int*)d_in[1];
    const float* wsrc = (const float*)d_in[2];
    const float* wdst = (const float*)d_in[3];
    const float* bias = (const float*)d_in[4];
    float* out = (float*)d_out;

    // ws layout: ssrc(32KB) | sdst(32KB) | XT bf16 (8MB) | P bf16 (16MB)
    float* ssrc = (float*)d_ws;
    float* sdst = ssrc + BB * NN;
    unsigned short* xt = (unsigned short*)(sdst + BB * NN);
    unsigned short* P  = xt + (size_t)BB * HH * NN;

    prep_kernel<<<dim3(BB * (NN / 16)), dim3(512), 0, stream>>>(x, wsrc, wdst, ssrc, sdst, xt);
    softmax_kernel<<<dim3(BB * NN / 4), dim3(256), 0, stream>>>(ssrc, sdst, adj, bias, P);
    pv_kernel<<<dim3(BB * 4 * 8), dim3(512), 0, stream>>>(P, xt, out);
}

// Round 17
// 36.961 us; speedup vs baseline: 1.4469x; 1.0124x over previous
//
#include <hip/hip_runtime.h>
#include <hip/hip_bf16.h>

#define BB 8
#define NN 1024
#define HH 512
#define NEG 0.2f

typedef float f32x4 __attribute__((ext_vector_type(4)));
typedef float f32x16 __attribute__((ext_vector_type(16)));
typedef short bf16x8 __attribute__((ext_vector_type(8)));
typedef int i32x4 __attribute__((ext_vector_type(4)));
typedef unsigned int u32;

__device__ __forceinline__ unsigned short f2bf(float f) {
    union { float f; u32 u; } a; a.f = f;
    u32 u = a.u;
    u += 0x7fffu + ((u >> 16) & 1u);   // round-to-nearest-even
    return (unsigned short)(u >> 16);
}

__device__ __forceinline__ void gload16(const void* g, void* l) {
    __builtin_amdgcn_global_load_lds(
        (const __attribute__((address_space(1))) unsigned int*)g,
        (__attribute__((address_space(3))) unsigned int*)l, 16, 0, 0);
}

// Kernel 1: per (batch, 16-row j-tile): s_src/s_dst dots + X^T bf16 [b][h][j]
__global__ __launch_bounds__(512) void prep_kernel(
    const float* __restrict__ x, const float* __restrict__ wsrc,
    const float* __restrict__ wdst, float* __restrict__ ssrc,
    float* __restrict__ sdst, unsigned short* __restrict__ xt)
{
    __shared__ __align__(16) unsigned short lt[16][528];

    int bid = blockIdx.x;
    int b = bid & 7;
    int j0 = (bid >> 3) * 16;
    int t = threadIdx.x;
    int r = t >> 5;            // 0..15: row in tile (32 threads per row)
    int l = t & 31;

    const float* xrow = x + ((size_t)(b * NN + j0 + r)) * HH;
    float psrc = 0.f, pdst = 0.f;
    #pragma unroll
    for (int q = 0; q < 4; ++q) {
        int h = q * 128 + l * 4;
        f32x4 v = __builtin_nontemporal_load((const f32x4*)(xrow + h));
        f32x4 a = *(const f32x4*)(wsrc + h);
        f32x4 d = *(const f32x4*)(wdst + h);
        psrc += v[0]*a[0] + v[1]*a[1] + v[2]*a[2] + v[3]*a[3];
        pdst += v[0]*d[0] + v[1]*d[1] + v[2]*d[2] + v[3]*d[3];
        u32 lo = (u32)f2bf(v[0]) | ((u32)f2bf(v[1]) << 16);
        u32 hi = (u32)f2bf(v[2]) | ((u32)f2bf(v[3]) << 16);
        *(u32*)&lt[r][h + 0] = lo;
        *(u32*)&lt[r][h + 2] = hi;
    }
    #pragma unroll
    for (int k = 1; k < 32; k <<= 1) {
        psrc += __shfl_xor(psrc, k);
        pdst += __shfl_xor(pdst, k);
    }
    if (l == 0) {
        ssrc[b * NN + j0 + r] = psrc;
        sdst[b * NN + j0 + r] = pdst;
    }
    __syncthreads();

    unsigned short v[16];
    #pragma unroll
    for (int rr = 0; rr < 16; ++rr) v[rr] = lt[rr][t];
    unsigned short* dst = xt + ((size_t)(b * HH + t)) * NN + j0;
    #pragma unroll
    for (int q = 0; q < 2; ++q) {
        bf16x8 pk;
        #pragma unroll
        for (int e = 0; e < 8; ++e) pk[e] = (short)v[q*8 + e];
        *(bf16x8*)(dst + q * 8) = pk;
    }
}

// Kernel 2 v2 (esum): UNNORMALIZED exp scores, single pass, no max subtraction.
// Range analysis: |s| <~ 8 => exp(s) <= ~3e3, row sum <= ~3e6 (fp32-safe);
// masked entries are exact 0 via cndmask; diagonal guarantees sum > 0.
// Writes E (bf16, unnormalized) + invl[b][i] = 1/sum. Saves the whole max pass
// (6 shuffles + 32 VALU) and kills sc[16] register pressure (single-pass).
__global__ __launch_bounds__(256) void esum_kernel(
    const float* __restrict__ ssrc, const float* __restrict__ sdst,
    const int* __restrict__ adj, const float* __restrict__ bptr,
    unsigned short* __restrict__ E, float* __restrict__ invl)
{
    __shared__ __align__(16) float sd[NN];

    int bid = blockIdx.x;
    int b = bid & 7;
    int r0 = (bid >> 3) * 4;
    int t = threadIdx.x;
    int lane = t & 63;
    int w = t >> 6;

    *(f32x4*)&sd[t * 4] = *(const f32x4*)&sdst[b * NN + t * 4];
    __syncthreads();

    int ig = r0 + w;
    float si = ssrc[b * NN + ig] + bptr[0];
    const int* arow = adj + ((size_t)b * NN + ig) * NN;
    unsigned short* erow = E + ((size_t)b * NN + ig) * NN;

    float sum = 0.f;
    #pragma unroll
    for (int it = 0; it < 4; ++it) {
        int j = it * 256 + lane * 4;
        i32x4 a4 = __builtin_nontemporal_load((const i32x4*)(arow + j));
        f32x4 sv = *(const f32x4*)&sd[j];
        float e[4];
        #pragma unroll
        for (int k = 0; k < 4; ++k) {
            float s = si + sv[k];
            float lk = fmaxf(s, NEG * s);          // leaky: max(s, 0.2s)
            float ev = __expf(lk);
            e[k] = (a4[k] != 0 || (j + k) == ig) ? ev : 0.f;
            sum += e[k];
        }
        u32 lo = (u32)f2bf(e[0]) | ((u32)f2bf(e[1]) << 16);
        u32 hi = (u32)f2bf(e[2]) | ((u32)f2bf(e[3]) << 16);
        *(uint2*)(erow + j) = make_uint2(lo, hi);
    }
    #pragma unroll
    for (int k = 1; k < 64; k <<= 1) sum += __shfl_xor(sum, k);
    if (lane == 0) invl[b * NN + ig] = 1.f / sum;
}

// Kernel 3 v5.4 = v5.3 + epilogue normalization by invl[i] (moved out of esum).
__global__ __launch_bounds__(512) void pv_kernel(
    const unsigned short* __restrict__ P, const unsigned short* __restrict__ xt,
    const float* __restrict__ invl, float* __restrict__ out)
{
    __shared__ __align__(16) unsigned short LDSq[3 * 8192 * 2]; // 96KB
    unsigned short* As = LDSq;               // 3 bufs x 16KB  [128h][64k] swizzled
    unsigned short* Bs = LDSq + 3 * 8192;    // 3 bufs x 16KB  [128i][64k] swizzled

    int bid = blockIdx.x;
    int b = bid & 7;              // XCD-affine
    int tt = bid >> 3;            // 0..31
    int h0 = (tt & 3) * 128;
    int i0 = (tt >> 2) * 128;
    int t = threadIdx.x;
    int lane = t & 63;
    int w = t >> 6;
    int ks = w >> 2;              // parity group: 0 = even K-steps, 1 = odd
    int wsub = w & 3;
    int wm = wsub & 1;            // h-half (64)
    int wn = wsub >> 1;           // i-half (64)
    int r32 = lane & 31;
    int hi = lane >> 5;

    int row0 = t >> 3;
    int c = t & 7;
    int sj = (c ^ (row0 & 7)) * 8;
    const unsigned short* gA0 = xt + ((size_t)(b * HH + h0 + row0)) * NN + sj;
    const unsigned short* gA1 = gA0 + (size_t)64 * NN;
    const unsigned short* gB0 = P + ((size_t)(b * NN + i0 + row0)) * NN + sj;
    const unsigned short* gB1 = gB0 + (size_t)64 * NN;
    unsigned short* lA0 = As + t * 8;          // rows 0..63
    unsigned short* lA1 = As + 4096 + t * 8;   // rows 64..127
    unsigned short* lB0 = Bs + t * 8;
    unsigned short* lB1 = Bs + 4096 + t * 8;

    const char* Ab[2]; int aswz[2];
    #pragma unroll
    for (int ma = 0; ma < 2; ++ma) {
        int row = wm * 64 + ma * 32 + r32;
        Ab[ma] = (const char*)As + row * 128;
        aswz[ma] = (row & 7) << 4;
    }
    const char* Bb[2]; int bswz[2];
    #pragma unroll
    for (int nb = 0; nb < 2; ++nb) {
        int row = wn * 64 + nb * 32 + r32;
        Bb[nb] = (const char*)Bs + row * 128;
        bswz[nb] = (row & 7) << 4;
    }

    f32x16 acc00 = {}, acc01 = {}, acc10 = {}, acc11 = {};

    auto stage = [&](int p, int js) {
        int joff = js * 64;
        gload16(gA0 + joff, lA0 + p * 8192);
        gload16(gA1 + joff, lA1 + p * 8192);
        gload16(gB0 + joff, lB0 + p * 8192);
        gload16(gB1 + joff, lB1 + p * 8192);
    };
    auto compute = [&](int p) {
        int ofs = p * 16384;
        __builtin_amdgcn_s_setprio(1);
        #pragma unroll
        for (int cc = 0; cc < 4; ++cc) {
            int koff = cc * 32 + hi * 16;
            bf16x8 af0 = *(const bf16x8*)(Ab[0] + (koff ^ aswz[0]) + ofs);
            bf16x8 af1 = *(const bf16x8*)(Ab[1] + (koff ^ aswz[1]) + ofs);
            bf16x8 bf0 = *(const bf16x8*)(Bb[0] + (koff ^ bswz[0]) + ofs);
            bf16x8 bf1 = *(const bf16x8*)(Bb[1] + (koff ^ bswz[1]) + ofs);
            acc00 = __builtin_amdgcn_mfma_f32_32x32x16_bf16(af0, bf0, acc00, 0, 0, 0);
            acc01 = __builtin_amdgcn_mfma_f32_32x32x16_bf16(af0, bf1, acc01, 0, 0, 0);
            acc10 = __builtin_amdgcn_mfma_f32_32x32x16_bf16(af1, bf0, acc10, 0, 0, 0);
            acc11 = __builtin_amdgcn_mfma_f32_32x32x16_bf16(af1, bf1, acc11, 0, 0, 0);
        }
        __builtin_amdgcn_s_setprio(0);
    };

    stage(0, 0);
    stage(1, 1);
    #pragma unroll
    for (int js = 0; js < 16; ++js) {
        if (js < 15) asm volatile("s_waitcnt vmcnt(4)" ::: "memory");
        else         asm volatile("s_waitcnt vmcnt(0)" ::: "memory");
        __builtin_amdgcn_sched_barrier(0);
        __builtin_amdgcn_s_barrier();
        __builtin_amdgcn_sched_barrier(0);
        if (js + 2 < 16) stage((js + 2) % 3, js + 2);
        if ((js & 1) == ks) compute(js % 3);
    }

    __syncthreads();   // red aliases As/Bs: all js=15 LDS reads retire first

    float* red = (float*)LDSq;
    int ridx = (wsub * 64 + lane) * 68;
    if (ks == 1) {
        #pragma unroll
        for (int fq = 0; fq < 4; ++fq) {
            const f32x16* a = fq == 0 ? &acc00 : fq == 1 ? &acc01 : fq == 2 ? &acc10 : &acc11;
            #pragma unroll
            for (int q = 0; q < 4; ++q)
                *(f32x4*)(red + ridx + fq * 16 + q * 4) =
                    (f32x4){(*a)[q*4+0], (*a)[q*4+1], (*a)[q*4+2], (*a)[q*4+3]};
        }
    }
    __syncthreads();
    if (ks == 0) {
        // epilogue normalization: i-column scale by invl[i]
        float il0 = invl[b * NN + i0 + wn * 64 + r32];        // nb = 0
        float il1 = invl[b * NN + i0 + wn * 64 + 32 + r32];   // nb = 1
        #pragma unroll
        for (int fq = 0; fq < 4; ++fq) {
            f32x16* a = fq == 0 ? &acc00 : fq == 1 ? &acc01 : fq == 2 ? &acc10 : &acc11;
            #pragma unroll
            for (int q = 0; q < 4; ++q) {
                f32x4 v = *(const f32x4*)(red + ridx + fq * 16 + q * 4);
                (*a)[q*4+0] += v[0]; (*a)[q*4+1] += v[1];
                (*a)[q*4+2] += v[2]; (*a)[q*4+3] += v[3];
            }
        }
        acc00 *= il0; acc10 *= il0;
        acc01 *= il1; acc11 *= il1;
        // D layout (32x32): col(i) = lane&31, row(h) = (reg&3) + 8*(reg>>2) + 4*hi
        #pragma unroll
        for (int ma = 0; ma < 2; ++ma) {
            #pragma unroll
            for (int nb = 0; nb < 2; ++nb) {
                const f32x16* a = ma == 0 ? (nb == 0 ? &acc00 : &acc01)
                                          : (nb == 0 ? &acc10 : &acc11);
                int i = i0 + wn * 64 + nb * 32 + r32;
                float* drow = out + ((size_t)(b * NN + i)) * HH + h0 + wm * 64 + ma * 32;
                #pragma unroll
                for (int q = 0; q < 4; ++q) {
                    f32x4 v = {(*a)[q*4+0], (*a)[q*4+1], (*a)[q*4+2], (*a)[q*4+3]};
                    __builtin_nontemporal_store(v, (f32x4*)(drow + q * 8 + hi * 4));
                }
            }
        }
    }
}

extern "C" void kernel_launch(void* const* d_in, const int* in_sizes, int n_in,
                              void* d_out, int out_size, void* d_ws, size_t ws_size,
                              hipStream_t stream) {
    const float* x    = (const float*)d_in[0];
    const int*   adj  = (const int*)d_in[1];
    const float* wsrc = (const float*)d_in[2];
    const float* wdst = (const float*)d_in[3];
    const float* bias = (const float*)d_in[4];
    float* out = (float*)d_out;

    // ws layout: ssrc(32KB) | sdst(32KB) | XT bf16 (8MB) | E bf16 (16MB) | invl(32KB)
    float* ssrc = (float*)d_ws;
    float* sdst = ssrc + BB * NN;
    unsigned short* xt = (unsigned short*)(sdst + BB * NN);
    unsigned short* E  = xt + (size_t)BB * HH * NN;
    float* invl = (float*)(E + (size_t)BB * NN * NN);

    prep_kernel<<<dim3(BB * (NN / 16)), dim3(512), 0, stream>>>(x, wsrc, wdst, ssrc, sdst, xt);
    esum_kernel<<<dim3(BB * NN / 4), dim3(256), 0, stream>>>(ssrc, sdst, adj, bias, E, invl);
    pv_kernel<<<dim3(BB * 4 * 8), dim3(512), 0, stream>>>(E, xt, invl, out);
}